// Round 1
// baseline (2697.109 us; speedup 1.0000x reference)
//
#include <hip/hip_runtime.h>
#include <math.h>

#define BB 16
#define NN 512
#define DIN 128
#define DM 256
#define NH 8
#define DH 32
#define FF 1024
#define DOUT 128
#define NHOP 258
#define NEDGE 27
#define ROWS (BB*NN)   // 8192

// ---------------- node embed: h = x @ node_W + node_b ----------------
__global__ void k_node(const float* __restrict__ x, const float* __restrict__ W,
                       const float* __restrict__ bias, float* __restrict__ h) {
    int row = blockIdx.x;
    int col = threadIdx.x;           // 256
    __shared__ float xs[DIN];
    if (col < DIN) xs[col] = x[row*DIN + col];
    __syncthreads();
    float acc = bias[col];
    #pragma unroll 4
    for (int c = 0; c < DIN; ++c) acc += xs[c] * W[c*DM + col];
    h[row*DM + col] = acc;
}

// ---------------- layernorm over DM=256, block=256 ----------------
__global__ void k_ln(const float* __restrict__ in, const float* __restrict__ g,
                     const float* __restrict__ bta, float* __restrict__ out) {
    int row = blockIdx.x;
    int t = threadIdx.x;
    __shared__ float red[DM];
    float v = in[row*DM + t];
    red[t] = v; __syncthreads();
    for (int s = 128; s > 0; s >>= 1) { if (t < s) red[t] += red[t+s]; __syncthreads(); }
    float mean = red[0] * (1.0f/DM);
    __syncthreads();
    float d = v - mean;
    red[t] = d*d; __syncthreads();
    for (int s = 128; s > 0; s >>= 1) { if (t < s) red[t] += red[t+s]; __syncthreads(); }
    float var = red[0] * (1.0f/DM);
    out[row*DM + t] = d * rsqrtf(var + 1e-5f) * g[t] + bta[t];
}

// ---------------- fused q/k/v projection, writes [B,H,N,DH] layout ----------------
__global__ void k_qkv(const float* __restrict__ y,
                      const float* __restrict__ Wq, const float* __restrict__ bq,
                      const float* __restrict__ Wk, const float* __restrict__ bk,
                      const float* __restrict__ Wv, const float* __restrict__ bv,
                      float* __restrict__ q, float* __restrict__ k, float* __restrict__ v) {
    int row = blockIdx.x;
    int col = threadIdx.x;
    __shared__ float ys[DM];
    ys[col] = y[row*DM + col];
    __syncthreads();
    float aq = bq[col], ak = bk[col], av = bv[col];
    for (int c = 0; c < DM; ++c) {
        float yc = ys[c];
        aq += yc * Wq[c*DM + col];
        ak += yc * Wk[c*DM + col];
        av += yc * Wv[c*DM + col];
    }
    int b = row >> 9, n = row & (NN-1);
    int hh = col >> 5, d = col & (DH-1);
    int o = ((b*NH + hh)*NN + n)*DH + d;
    q[o] = aq; k[o] = ak; v[o] = av;
}

// ---------------- khT[b,h,m,j] = k[b,h,j,:] . Kh[h,m,:] ----------------
__global__ void k_kht(const float* __restrict__ k, const float* __restrict__ k_hop,
                      float* __restrict__ kht) {
    int bm = blockIdx.x;             // bh*NHOP + m
    int m = bm % NHOP;
    int bh = bm / NHOP;
    int hh = bh & (NH-1);
    __shared__ float khs[DH];
    if (threadIdx.x < DH) khs[threadIdx.x] = k_hop[m*DM + hh*DH + threadIdx.x];
    __syncthreads();
    for (int j = threadIdx.x; j < NN; j += 256) {
        const float* kj = k + (bh*NN + j)*DH;
        float acc = 0.f;
        #pragma unroll
        for (int d = 0; d < DH; ++d) acc += kj[d] * khs[d];
        kht[bm*NN + j] = acc;
    }
}

// ---------------- fused attention: one block per (b,h,i) query row ----------------
__global__ __launch_bounds__(256) void k_attn(
    const float* __restrict__ q, const float* __restrict__ k, const float* __restrict__ v,
    const float* __restrict__ kht, const int* __restrict__ dist, const int* __restrict__ edge,
    const unsigned char* __restrict__ mask,
    const float* __restrict__ q_hop, const float* __restrict__ q_edge,
    const float* __restrict__ k_edge, const float* __restrict__ v_hop,
    const float* __restrict__ v_edge, float* __restrict__ ctx)
{
    int bi = blockIdx.x;            // bh*N + i
    int i  = bi & (NN-1);
    int bh = bi >> 9;
    int b  = bh >> 3, hh = bh & (NH-1);
    int t  = threadIdx.x;

    __shared__ float qi[DH], ki[DH];
    __shared__ float qh_i[NHOP];
    __shared__ float qece[NEDGE];
    __shared__ float sc[NN];
    __shared__ int   mj[NN], ej[NN];
    __shared__ float red[256];

    if (t < DH) {
        qi[t] = q[(bh*NN + i)*DH + t];
        ki[t] = k[(bh*NN + i)*DH + t];
    }
    __syncthreads();

    // row-local bias tables
    for (int m = t; m < NHOP; m += 256) {
        const float* Qh = q_hop + m*DM + hh*DH;
        float a = 0.f;
        #pragma unroll
        for (int d = 0; d < DH; ++d) a += qi[d] * Qh[d];
        qh_i[m] = a;
    }
    if (t < NEDGE) {
        const float* Qe = q_edge + t*DM + hh*DH;
        const float* Ke = k_edge + t*DM + hh*DH;
        float a = 0.f, c = 0.f;
        #pragma unroll
        for (int d = 0; d < DH; ++d) { a += qi[d]*Qe[d]; c += ki[d]*Ke[d]; }
        qece[t] = a + c;   // query_edge + key_edge (both row-i local)
    }
    __syncthreads();

    // scores
    const float scale = 0.17677669529663687f;  // 1/sqrt(32)
    for (int j = t; j < NN; j += 256) {
        int dv = dist[(b*NN + i)*NN + j];
        int ev = edge[(b*NN + i)*NN + j];
        int m = dv > 256 ? 256 : dv; if (dv == -1) m = 257;
        int e = ev > 25  ? 25  : ev; if (ev == -1) e = 26;
        mj[j] = m; ej[j] = e;
        const float* kj = k + (bh*NN + j)*DH;
        float a = 0.f;
        #pragma unroll
        for (int d = 0; d < DH; ++d) a += qi[d]*kj[d];
        a += qh_i[m] + kht[(bh*NHOP + m)*NN + j] + qece[e];
        a *= scale;
        if (mask[b*NN + j]) a = -INFINITY;
        sc[j] = a;
    }
    __syncthreads();

    // softmax (unnormalized exp in sc, inv folded at end)
    float lm = fmaxf(sc[t], sc[t+256]);
    red[t] = lm; __syncthreads();
    for (int s = 128; s > 0; s >>= 1) { if (t < s) red[t] = fmaxf(red[t], red[t+s]); __syncthreads(); }
    float mx = red[0]; __syncthreads();
    float p0 = expf(sc[t]      - mx);
    float p1 = expf(sc[t+256]  - mx);
    sc[t] = p0; sc[t+256] = p1;
    red[t] = p0 + p1; __syncthreads();
    for (int s = 128; s > 0; s >>= 1) { if (t < s) red[t] += red[t+s]; __syncthreads(); }
    float inv = 1.0f / red[0];
    __syncthreads();

    // ctx_i[d] = inv * sum_j p_j * ( v[j,d] + Vh[mj,d] + Ve[ej,d] )
    int d = t & (DH-1), c = t >> 5;       // 32 d-lanes x 8 j-chunks
    const float* vhb = v_hop  + hh*DH + d;
    const float* veb = v_edge + hh*DH + d;
    float acc = 0.f;
    int j0 = c*64;
    for (int j = j0; j < j0 + 64; ++j) {
        float w = sc[j];
        float vv = v[(bh*NN + j)*DH + d] + vhb[mj[j]*DM] + veb[ej[j]*DM];
        acc += w * vv;
    }
    red[t] = acc;
    __syncthreads();
    if (t < DH) {
        float a = 0.f;
        #pragma unroll
        for (int c2 = 0; c2 < 8; ++c2) a += red[c2*32 + t];
        ctx[(b*NN + i)*DM + hh*DH + t] = a * inv;
    }
}

// ---------------- h += in @ W + b   (DM x DM) ----------------
__global__ void k_gemm_res(const float* __restrict__ in, const float* __restrict__ W,
                           const float* __restrict__ bias, float* __restrict__ h) {
    int row = blockIdx.x, col = threadIdx.x;
    __shared__ float s[DM];
    s[col] = in[row*DM + col];
    __syncthreads();
    float acc = bias[col];
    for (int c = 0; c < DM; ++c) acc += s[c] * W[c*DM + col];
    h[row*DM + col] += acc;
}

// ---------------- t = gelu(y @ W1 + b1)  (DM x FF) ----------------
__global__ void k_ffn1(const float* __restrict__ y, const float* __restrict__ W1,
                       const float* __restrict__ b1, float* __restrict__ t) {
    int row = blockIdx.x, tid = threadIdx.x;
    __shared__ float s[DM];
    s[tid] = y[row*DM + tid];
    __syncthreads();
    for (int cc = 0; cc < 4; ++cc) {
        int col = tid + cc*256;
        float acc = b1[col];
        for (int c = 0; c < DM; ++c) acc += s[c] * W1[c*FF + col];
        // exact gelu: 0.5*x*(1+erf(x/sqrt(2)))
        t[row*FF + col] = 0.5f * acc * (1.0f + erff(acc * 0.70710678118654752f));
    }
}

// ---------------- h += t @ W2 + b2  (FF x DM) ----------------
__global__ void k_ffn2(const float* __restrict__ t, const float* __restrict__ W2,
                       const float* __restrict__ b2, float* __restrict__ h) {
    int row = blockIdx.x, tid = threadIdx.x;
    __shared__ float s[FF];
    for (int cc = 0; cc < 4; ++cc) s[tid + cc*256] = t[row*FF + tid + cc*256];
    __syncthreads();
    float acc = b2[tid];
    for (int c = 0; c < FF; ++c) acc += s[c] * W2[c*DM + tid];
    h[row*DM + tid] += acc;
}

// ---------------- out = y @ out_W + out_b  (DM x DOUT) ----------------
__global__ void k_out(const float* __restrict__ y, const float* __restrict__ W,
                      const float* __restrict__ bias, float* __restrict__ out) {
    int row = blockIdx.x, tid = threadIdx.x;   // 128 threads
    __shared__ float s[DM];
    s[tid] = y[row*DM + tid];
    s[tid + 128] = y[row*DM + tid + 128];
    __syncthreads();
    float acc = bias[tid];
    for (int c = 0; c < DM; ++c) acc += s[c] * W[c*DOUT + tid];
    out[row*DOUT + tid] = acc;
}

extern "C" void kernel_launch(void* const* d_in, const int* in_sizes, int n_in,
                              void* d_out, int out_size, void* d_ws, size_t ws_size,
                              hipStream_t stream) {
    const float* x     = (const float*)d_in[0];
    const unsigned char* mask = (const unsigned char*)d_in[1];
    const int*   dist  = (const int*)d_in[2];
    const int*   edge  = (const int*)d_in[3];
    const float* node_W = (const float*)d_in[4];
    const float* node_b = (const float*)d_in[5];
    const float* ln1_g = (const float*)d_in[6];
    const float* ln1_b = (const float*)d_in[7];
    const float* Wq = (const float*)d_in[8];
    const float* bq = (const float*)d_in[9];
    const float* Wk = (const float*)d_in[10];
    const float* bk = (const float*)d_in[11];
    const float* Wv = (const float*)d_in[12];
    const float* bv = (const float*)d_in[13];
    const float* Wo = (const float*)d_in[14];
    const float* bo = (const float*)d_in[15];
    const float* ln2_g = (const float*)d_in[16];
    const float* ln2_b = (const float*)d_in[17];
    const float* W1 = (const float*)d_in[18];
    const float* b1 = (const float*)d_in[19];
    const float* W2 = (const float*)d_in[20];
    const float* b2 = (const float*)d_in[21];
    const float* q_hop  = (const float*)d_in[22];
    const float* q_edge = (const float*)d_in[23];
    const float* k_hop  = (const float*)d_in[24];
    const float* k_edge = (const float*)d_in[25];
    const float* v_hop  = (const float*)d_in[26];
    const float* v_edge = (const float*)d_in[27];
    const float* fln_g = (const float*)d_in[28];
    const float* fln_b = (const float*)d_in[29];
    const float* out_W = (const float*)d_in[30];
    const float* out_b = (const float*)d_in[31];
    float* out = (float*)d_out;

    float* ws = (float*)d_ws;
    // workspace layout (floats)
    float* h   = ws + 0;                         //  8192*256 = 2,097,152
    float* y   = ws + 2097152;                   //  2,097,152
    float* q   = ws + 4194304;                   //  2,097,152  [B,H,N,DH]
    float* k   = ws + 6291456;                   //  2,097,152
    float* v   = ws + 8388608;                   //  2,097,152
    float* ctx = ws + 10485760;                  //  2,097,152
    float* kht = ws + 12582912;                  // 16,908,288  [B,H,NHOP,N]
    float* ffn = kht;                            //  8,388,608  (aliases kht, dead by then)

    k_node<<<ROWS, 256, 0, stream>>>(x, node_W, node_b, h);
    k_ln<<<ROWS, 256, 0, stream>>>(h, ln1_g, ln1_b, y);
    k_qkv<<<ROWS, 256, 0, stream>>>(y, Wq, bq, Wk, bk, Wv, bv, q, k, v);
    k_kht<<<BB*NH*NHOP, 256, 0, stream>>>(k, k_hop, kht);
    k_attn<<<BB*NH*NN, 256, 0, stream>>>(q, k, v, kht, dist, edge, mask,
                                         q_hop, q_edge, k_edge, v_hop, v_edge, ctx);
    k_gemm_res<<<ROWS, 256, 0, stream>>>(ctx, Wo, bo, h);
    k_ln<<<ROWS, 256, 0, stream>>>(h, ln2_g, ln2_b, y);
    k_ffn1<<<ROWS, 256, 0, stream>>>(y, W1, b1, ffn);
    k_ffn2<<<ROWS, 256, 0, stream>>>(ffn, W2, b2, h);
    k_ln<<<ROWS, 256, 0, stream>>>(h, fln_g, fln_b, y);
    k_out<<<ROWS, 128, 0, stream>>>(y, out_W, out_b, out);
}